// Round 10
// baseline (149.038 us; speedup 1.0000x reference)
//
#include <hip/hip_runtime.h>

#define NCOMP 19
#define NB    4096
#define PI_F  3.14159265358979323846f

typedef float f32x4 __attribute__((ext_vector_type(4)));

// ---- compile-time eigenvector table: V[k][j] = sin((k+1)(j+1)pi/20)/sqrt(10) ----
__device__ __forceinline__ constexpr float vconst(int k, int j) {
  constexpr float S[21] = {
    0.0f, 0.15643446504023087f, 0.3090169943749474f, 0.45399049973954675f,
    0.5877852522924731f, 0.7071067811865476f, 0.8090169943749475f,
    0.8910065241883679f, 0.9510565162951535f, 0.9876883405951378f, 1.0f,
    0.9876883405951378f, 0.9510565162951535f, 0.8910065241883679f,
    0.8090169943749475f, 0.7071067811865476f, 0.5877852522924731f,
    0.45399049973954675f, 0.3090169943749474f, 0.15643446504023087f, 0.0f};
  int m = ((k + 1) * (j + 1)) % 40;
  float s = (m <= 20) ? S[m] : -S[m - 20];
  return s * 0.31622776601683794f;
}

// ---- DPP wave64 inclusive scan (VALU-only, no DS traffic) ----
template <int CTRL, int RMASK>
__device__ __forceinline__ float dpp_add(float x) {
  int v = __builtin_amdgcn_update_dpp(0, __float_as_int(x), CTRL, RMASK, 0xf, true);
  return x + __int_as_float(v);
}
__device__ __forceinline__ float wave_iscan(float x) {
  x = dpp_add<0x111, 0xf>(x);   // row_shr:1
  x = dpp_add<0x112, 0xf>(x);   // row_shr:2
  x = dpp_add<0x114, 0xf>(x);   // row_shr:4
  x = dpp_add<0x118, 0xf>(x);   // row_shr:8
  x = dpp_add<0x142, 0xa>(x);   // row_bcast:15 -> rows 1,3
  x = dpp_add<0x143, 0xc>(x);   // row_bcast:31 -> rows 2,3
  return x;
}

// one block (4 waves) = one (batch, system); thread t owns output steps 4t..4t+3.
__global__ __launch_bounds__(256) void spm_fused(
    const float* __restrict__ xin, const float* __restrict__ iseq,
    const float* __restrict__ An, const float* __restrict__ Bn,
    const float* __restrict__ Ap, const float* __restrict__ Bp,
    float* __restrict__ out)
{
  __shared__ float xs0[NCOMP];
  __shared__ float4 mcv[NCOMP];                   // (gi, w*gi, log2 g, s0)
  __shared__ float2 mgw[NCOMP];                   // (g, w)
  __shared__ __align__(16) float wtot[NCOMP][4];  // per-wave scan totals

  const int t = threadIdx.x;
  const int lane = t & 63, wid = t >> 6;
  const int b = blockIdx.x >> 1, sys = blockIdx.x & 1;
  const float alpha = sys ? Ap[1] : An[1];
  const float ha    = 0.01f * alpha;

  if (t < NCOMP) xs0[t] = xin[(size_t)b * (2 * NCOMP) + sys * NCOMP + t];
  __syncthreads();

  if (t < NCOMP) {
    float ab = sys ? Bp[NCOMP - 1] : Bn[NCOMP - 1];
    float sk = sinf((float)(t + 1) * (PI_F / 40.0f));
    float z  = ha * (-4.0f * sk * sk);            // h*alpha*lambda_k
    float g  = 1.0f + z * (1.0f + z * (0.5f + z * ((1.0f/6.0f) + z * (1.0f/24.0f))));
    float S  = 1.0f + z * (0.5f + z * ((1.0f/6.0f) + z * (1.0f/24.0f)));
    float gi = 1.0f / g;
    float vlast = sinf((float)(((t + 1) * NCOMP) % 40) * (PI_F / 20.0f)) *
                  0.31622776601683794f;
    float w = 0.01f * S * ab * vlast;             // modal input weight
    float s0 = 0.0f;
#pragma unroll
    for (int j = 0; j < NCOMP; ++j)
      s0 = fmaf(sinf((float)(((t + 1) * (j + 1)) % 40) * (PI_F / 20.0f)) *
                    0.31622776601683794f, xs0[j], s0);
    mcv[t] = make_float4(gi, w * gi, __builtin_log2f(g), s0);
    mgw[t] = make_float2(g, w);
  }
  __syncthreads();

  const float4 iv = *reinterpret_cast<const float4*>(iseq + (size_t)b * 1024 + t * 4);
  const float pos = (float)(4 * t);

  // Phase A: per-mode weighted wave-local scan (DPP, no DS)
  float Cp[NCOMP];
#pragma unroll
  for (int k = 0; k < NCOMP; ++k) {
    const float4 c = mcv[k];
    float r = iv.x + c.x * (iv.y + c.x * (iv.z + c.x * iv.w));
    float a = __builtin_exp2f(-pos * c.z) * r;
    float v = wave_iscan(a);
    if (lane == 63) wtot[k][wid] = v;
    Cp[k] = v - a;
  }
  __syncthreads();

  // Phase B: modal start state + 4-step modal evolution (independent scalars)
  float sA[NCOMP], sB[NCOMP], sC[NCOMP], sD[NCOMP];
#pragma unroll
  for (int k = 0; k < NCOMP; ++k) {
    const float4 c = mcv[k];
    const float2 gw = mgw[k];
    float4 q = *reinterpret_cast<const float4*>(&wtot[k][0]);
    float C = Cp[k];
    if (wid > 0) C += q.x;
    if (wid > 1) C += q.y;
    if (wid > 2) C += q.z;
    float s = __builtin_exp2f(pos * c.z) * fmaf(c.y, C, c.w);   // s_k(4t)
    sA[k] = fmaf(gw.x, s,     gw.y * iv.x);   // s_k(4t+1)
    sB[k] = fmaf(gw.x, sA[k], gw.y * iv.y);
    sC[k] = fmaf(gw.x, sB[k], gw.y * iv.z);
    sD[k] = fmaf(gw.x, sC[k], gw.y * iv.w);
  }

  // Emit: per row-pair (j, 18-j) via parity folding; stores interleave compute.
  float* orow = out + ((size_t)b * (2 * NCOMP) + sys * NCOMP) * 1024 + t * 4;
#pragma unroll
  for (int jj = 0; jj < 9; ++jj) {
    float E0 = 0.f, E1 = 0.f, E2 = 0.f, E3 = 0.f;
    float O0 = 0.f, O1 = 0.f, O2 = 0.f, O3 = 0.f;
#pragma unroll
    for (int k = 0; k < NCOMP; k += 2) {          // even modes: symmetric
      const float vk = vconst(k, jj);
      E0 = fmaf(sA[k], vk, E0); E1 = fmaf(sB[k], vk, E1);
      E2 = fmaf(sC[k], vk, E2); E3 = fmaf(sD[k], vk, E3);
    }
#pragma unroll
    for (int k = 1; k < NCOMP; k += 2) {          // odd modes: antisymmetric
      const float vk = vconst(k, jj);
      O0 = fmaf(sA[k], vk, O0); O1 = fmaf(sB[k], vk, O1);
      O2 = fmaf(sC[k], vk, O2); O3 = fmaf(sD[k], vk, O3);
    }
    f32x4 vp = { E0 + O0, E1 + O1, E2 + O2, E3 + O3 };
    f32x4 vm = { E0 - O0, E1 - O1, E2 - O2, E3 - O3 };
    __builtin_nontemporal_store(vp, reinterpret_cast<f32x4*>(orow + (size_t)jj * 1024));
    __builtin_nontemporal_store(vm, reinterpret_cast<f32x4*>(orow + (size_t)(18 - jj) * 1024));
  }
  {   // center row j=9: odd modes vanish
    float E0 = 0.f, E1 = 0.f, E2 = 0.f, E3 = 0.f;
#pragma unroll
    for (int k = 0; k < NCOMP; k += 2) {
      const float vk = vconst(k, 9);
      E0 = fmaf(sA[k], vk, E0); E1 = fmaf(sB[k], vk, E1);
      E2 = fmaf(sC[k], vk, E2); E3 = fmaf(sD[k], vk, E3);
    }
    f32x4 vc = { E0, E1, E2, E3 };
    __builtin_nontemporal_store(vc, reinterpret_cast<f32x4*>(orow + (size_t)9 * 1024));
  }
}

extern "C" void kernel_launch(void* const* d_in, const int* in_sizes, int n_in,
                              void* d_out, int out_size, void* d_ws, size_t ws_size,
                              hipStream_t stream) {
  const float* x    = (const float*)d_in[0];
  const float* iseq = (const float*)d_in[1];
  const float* An   = (const float*)d_in[2];
  const float* Bn   = (const float*)d_in[3];
  const float* Ap   = (const float*)d_in[4];
  const float* Bp   = (const float*)d_in[5];
  float* out = (float*)d_out;

  spm_fused<<<NB * 2, 256, 0, stream>>>(x, iseq, An, Bn, Ap, Bp, out);
}

// Round 11
// 132.088 us; speedup vs baseline: 1.1283x; 1.1283x over previous
//
#include <hip/hip_runtime.h>

#define NCOMP 19
#define NB    4096

typedef float f32x4 __attribute__((ext_vector_type(4)));

// ---- compile-time tables ----
// S20[i] = sin(i*pi/20), i=0..20
constexpr float S20[21] = {
  0.0f, 0.15643446504023087f, 0.3090169943749474f, 0.45399049973954675f,
  0.5877852522924731f, 0.7071067811865476f, 0.8090169943749475f,
  0.8910065241883679f, 0.9510565162951535f, 0.9876883405951378f, 1.0f,
  0.9876883405951378f, 0.9510565162951535f, 0.8910065241883679f,
  0.8090169943749475f, 0.7071067811865476f, 0.5877852522924731f,
  0.45399049973954675f, 0.3090169943749474f, 0.15643446504023087f, 0.0f};

__host__ __device__ constexpr float sval(int m) {        // sin(m*pi/20), m in [0,40)
  return (m <= 20) ? S20[m] : -S20[m - 20];
}
__host__ __device__ constexpr float vconst(int k, int j) { // V[k][j]
  return sval(((k + 1) * (j + 1)) % 40) * 0.31622776601683794f;
}

struct Tabs { float v[NCOMP][NCOMP]; float lam[NCOMP]; };
__host__ __device__ constexpr Tabs make_tabs() {
  Tabs T{};
  for (int k = 0; k < NCOMP; ++k) {
    for (int j = 0; j < NCOMP; ++j) T.v[k][j] = vconst(k, j);
    T.lam[k] = -2.0f * (1.0f - sval((k + 11) % 40));     // -4 sin^2((k+1)pi/40)
  }
  return T;
}
__constant__ Tabs VT = make_tabs();

// ---- DPP wave64 inclusive scan (VALU-only) ----
template <int CTRL, int RMASK>
__device__ __forceinline__ float dpp_add(float x) {
  int v = __builtin_amdgcn_update_dpp(0, __float_as_int(x), CTRL, RMASK, 0xf, true);
  return x + __int_as_float(v);
}
__device__ __forceinline__ float wave_iscan(float x) {
  x = dpp_add<0x111, 0xf>(x);
  x = dpp_add<0x112, 0xf>(x);
  x = dpp_add<0x114, 0xf>(x);
  x = dpp_add<0x118, 0xf>(x);
  x = dpp_add<0x142, 0xa>(x);   // row_bcast:15
  x = dpp_add<0x143, 0xc>(x);   // row_bcast:31
  return x;
}

// reference-identical RK4 (setup only: input-response vector, 2 lanes/block)
__device__ __forceinline__ void derivf(const float* __restrict__ y, float a, float bin,
                                       float* __restrict__ k) {
#pragma unroll
  for (int j = 0; j < NCOMP; ++j) {
    float s = -2.0f * y[j];
    if (j > 0) s += y[j - 1];
    if (j < NCOMP - 1) s += y[j + 1];
    k[j] = a * s;
  }
  k[NCOMP - 1] += bin;
}
__device__ __forceinline__ void rk4f(float* __restrict__ x, float a, float bin) {
  const float h = 0.01f, h2 = 0.005f, h6 = 0.01f / 6.0f;
  float k[NCOMP], y[NCOMP], acc[NCOMP];
  derivf(x, a, bin, k);
#pragma unroll
  for (int j = 0; j < NCOMP; ++j) { acc[j] = k[j]; y[j] = fmaf(h2, k[j], x[j]); }
  derivf(y, a, bin, k);
#pragma unroll
  for (int j = 0; j < NCOMP; ++j) { acc[j] = fmaf(2.0f, k[j], acc[j]); y[j] = fmaf(h2, k[j], x[j]); }
  derivf(y, a, bin, k);
#pragma unroll
  for (int j = 0; j < NCOMP; ++j) { acc[j] = fmaf(2.0f, k[j], acc[j]); y[j] = fmaf(h, k[j], x[j]); }
  derivf(y, a, bin, k);
#pragma unroll
  for (int j = 0; j < NCOMP; ++j) x[j] = fmaf(h6, acc[j] + k[j], x[j]);
}

// one Horner stage: o = x + c * T * u,  T = tridiag(1,-2,1)
__device__ __forceinline__ void stage(float c, const float* __restrict__ u,
                                      const float* __restrict__ x,
                                      float* __restrict__ o) {
  o[0] = fmaf(c, fmaf(-2.0f, u[0], u[1]), x[0]);
#pragma unroll
  for (int j = 1; j < NCOMP - 1; ++j)
    o[j] = fmaf(c, fmaf(-2.0f, u[j], u[j - 1] + u[j + 1]), x[j]);
  o[NCOMP - 1] = fmaf(c, fmaf(-2.0f, u[NCOMP - 1], u[NCOMP - 2]), x[NCOMP - 1]);
}

// x <- R4(h*alpha*T) x + i*d   (algebraically == one RK4 step)
__device__ __forceinline__ void step_horner(float* __restrict__ x, float ha,
                                            const float4 d, float iin) {
  float t1[NCOMP], t2[NCOMP];
  stage(ha * 0.25f, x, x, t1);
  stage(ha * (1.0f / 3.0f), t1, x, t2);
  stage(ha * 0.5f, t2, x, t1);
  stage(ha, t1, x, x);
  x[15] = fmaf(iin, d.x, x[15]);
  x[16] = fmaf(iin, d.y, x[16]);
  x[17] = fmaf(iin, d.z, x[17]);
  x[18] = fmaf(iin, d.w, x[18]);
}

// one block (4 waves) = one (batch, system); thread t owns steps 4t..4t+3.
__global__ __launch_bounds__(256) void spm_fused(
    const float* __restrict__ xin, const float* __restrict__ iseq,
    const float* __restrict__ An, const float* __restrict__ Bn,
    const float* __restrict__ Ap, const float* __restrict__ Bp,
    float* __restrict__ out)
{
  __shared__ float xs0[NCOMP];
  __shared__ float4 mcv[NCOMP];                   // (gi, w*gi, log2 g, s0)
  __shared__ __align__(16) float wtot[NCOMP][4];
  __shared__ float4 dls[2];

  const int t = threadIdx.x;
  const int lane = t & 63, wid = t >> 6;
  const int b = blockIdx.x >> 1, sys = blockIdx.x & 1;
  const float alpha = sys ? Ap[1] : An[1];
  const float ha    = 0.01f * alpha;

  // issue input load early: HBM latency overlaps the prologue
  const float4 iv = *reinterpret_cast<const float4*>(iseq + (size_t)b * 1024 + t * 4);

  // input-response vector d (2 lanes)
  if (t < 2) {
    float al  = t ? Ap[1] : An[1];
    float abv = t ? Bp[NCOMP - 1] : Bn[NCOMP - 1];
    float z[NCOMP];
#pragma unroll
    for (int j = 0; j < NCOMP; ++j) z[j] = 0.0f;
    rk4f(z, al, abv);
    dls[t] = make_float4(z[15], z[16], z[17], z[18]);
  }
  if (t < NCOMP) xs0[t] = xin[(size_t)b * (2 * NCOMP) + sys * NCOMP + t];
  __syncthreads();

  if (t < NCOMP) {
    float ab = sys ? Bp[NCOMP - 1] : Bn[NCOMP - 1];
    float z  = ha * VT.lam[t];                    // h*alpha*lambda_k (const table)
    float g  = 1.0f + z * (1.0f + z * (0.5f + z * ((1.0f/6.0f) + z * (1.0f/24.0f))));
    float S  = 1.0f + z * (0.5f + z * ((1.0f/6.0f) + z * (1.0f/24.0f)));
    float gi = 1.0f / g;
    float s0 = 0.0f;
#pragma unroll
    for (int j = 0; j < NCOMP; ++j) s0 = fmaf(VT.v[t][j], xs0[j], s0);
    mcv[t] = make_float4(gi, 0.01f * S * ab * VT.v[t][NCOMP - 1] * gi,
                         __builtin_log2f(g), s0);
  }
  __syncthreads();

  const float4 dvec = dls[sys];
  const float pos = (float)(4 * t);

  // Phase A: per-mode weighted wave-local scan (DPP)
  float Cp[NCOMP];
#pragma unroll
  for (int k = 0; k < NCOMP; ++k) {
    const float4 c = mcv[k];
    float r = iv.x + c.x * (iv.y + c.x * (iv.z + c.x * iv.w));
    float a = __builtin_exp2f(-pos * c.z) * r;
    float v = wave_iscan(a);
    if (lane == 63) wtot[k][wid] = v;
    Cp[k] = v - a;
  }
  __syncthreads();

  // Phase B: cross-quarter offsets, reconstruct physical x0 (compile-time V)
  float x0[NCOMP];
#pragma unroll
  for (int j = 0; j < NCOMP; ++j) x0[j] = 0.0f;
#pragma unroll
  for (int k = 0; k < NCOMP; ++k) {
    const float4 c = mcv[k];
    float4 q = *reinterpret_cast<const float4*>(&wtot[k][0]);
    float C = Cp[k];
    if (wid > 0) C += q.x;
    if (wid > 1) C += q.y;
    if (wid > 2) C += q.z;
    float s = __builtin_exp2f(pos * c.z) * fmaf(c.y, C, c.w);
#pragma unroll
    for (int j = 0; j < NCOMP; ++j) x0[j] = fmaf(s, vconst(k, j), x0[j]);
  }
  if (t == 0) {
#pragma unroll
    for (int j = 0; j < NCOMP; ++j) x0[j] = xs0[j];
  }

  // 4 Horner steps, terminal nt-store burst (max store MLP — R9-proven)
  float b0[NCOMP], b1[NCOMP], b2[NCOMP], b3[NCOMP];
  step_horner(x0, ha, dvec, iv.x);
#pragma unroll
  for (int j = 0; j < NCOMP; ++j) b0[j] = x0[j];
  step_horner(x0, ha, dvec, iv.y);
#pragma unroll
  for (int j = 0; j < NCOMP; ++j) b1[j] = x0[j];
  step_horner(x0, ha, dvec, iv.z);
#pragma unroll
  for (int j = 0; j < NCOMP; ++j) b2[j] = x0[j];
  step_horner(x0, ha, dvec, iv.w);
#pragma unroll
  for (int j = 0; j < NCOMP; ++j) b3[j] = x0[j];

  float* orow = out + ((size_t)b * (2 * NCOMP) + sys * NCOMP) * 1024 + t * 4;
#pragma unroll
  for (int j = 0; j < NCOMP; ++j) {
    f32x4 v = { b0[j], b1[j], b2[j], b3[j] };
    __builtin_nontemporal_store(v, reinterpret_cast<f32x4*>(orow + (size_t)j * 1024));
  }
}

extern "C" void kernel_launch(void* const* d_in, const int* in_sizes, int n_in,
                              void* d_out, int out_size, void* d_ws, size_t ws_size,
                              hipStream_t stream) {
  const float* x    = (const float*)d_in[0];
  const float* iseq = (const float*)d_in[1];
  const float* An   = (const float*)d_in[2];
  const float* Bn   = (const float*)d_in[3];
  const float* Ap   = (const float*)d_in[4];
  const float* Bp   = (const float*)d_in[5];
  float* out = (float*)d_out;

  spm_fused<<<NB * 2, 256, 0, stream>>>(x, iseq, An, Bn, Ap, Bp, out);
}